// Round 5
// baseline (441.732 us; speedup 1.0000x reference)
//
#include <hip/hip_runtime.h>

typedef __attribute__((ext_vector_type(4))) float f32x4;
typedef __attribute__((ext_vector_type(8))) short s16x8;

// ---------- exact fp8 e4m3fn round-trip (RNE), matching ml_dtypes/jax ----------
__device__ __forceinline__ float qdq_e4m3(float v) {
    unsigned int u = __float_as_uint(v);
    unsigned int s = u & 0x80000000u;
    unsigned int a = u & 0x7fffffffu;
    if (a >= 0x3C800000u) {                 // |v| >= 2^-6 : normal e4m3 range
        unsigned int r = a + 0x7FFFFu + ((a >> 20) & 1u);
        r &= 0xFFF00000u;
        if (r > 0x43E00000u) r = 0x43E00000u;  // saturate at 448
        return __uint_as_float(s | r);
    } else {                                 // subnormal: grid of 2^-9
        float f = __uint_as_float(a);
        float m = rintf(f * 512.0f) * (1.0f / 512.0f);
        return __uint_as_float(s | __float_as_uint(m));
    }
}

__device__ __forceinline__ unsigned short f32_to_bf16_bits(float f) {
    unsigned int u = __float_as_uint(f);
    u += 0x7FFFu + ((u >> 16) & 1u);        // RNE
    return (unsigned short)(u >> 16);
}

// ---------- quantize x: per-row 1x64 tiles; 16 lanes per tile, float4/lane ----------
__global__ __launch_bounds__(256) void quant_x_kernel(const float* __restrict__ x,
                                                      unsigned short* __restrict__ xq,
                                                      long long n4) {
    long long g = (long long)blockIdx.x * 256 + threadIdx.x;
    if (g >= n4) return;
    f32x4 v = ((const f32x4*)x)[g];
    float a = fmaxf(fmaxf(fabsf(v.x), fabsf(v.y)), fmaxf(fabsf(v.z), fabsf(v.w)));
    a = fmaxf(a, __shfl_xor(a, 1));
    a = fmaxf(a, __shfl_xor(a, 2));
    a = fmaxf(a, __shfl_xor(a, 4));
    a = fmaxf(a, __shfl_xor(a, 8));
    float scale = fmaxf(a, 1e-12f) / 448.0f;
    ushort4 o;
    o.x = f32_to_bf16_bits(qdq_e4m3(v.x / scale) * scale);
    o.y = f32_to_bf16_bits(qdq_e4m3(v.y / scale) * scale);
    o.z = f32_to_bf16_bits(qdq_e4m3(v.z / scale) * scale);
    o.w = f32_to_bf16_bits(qdq_e4m3(v.w / scale) * scale);
    ((ushort4*)xq)[g] = o;
}

// ---------- quantize w: 64x64 blocks; one 256-thread block per weight block ----------
__global__ __launch_bounds__(256) void quant_w_kernel(const float* __restrict__ w,
                                                      unsigned short* __restrict__ wq,
                                                      int N, int K) {
    const int nb = blockIdx.y, kb = blockIdx.x;
    const int t = threadIdx.x;
    const int rgrp = t >> 4;
    const int cchk = t & 15;
    f32x4 v[4];
    float a = 0.0f;
#pragma unroll
    for (int i = 0; i < 4; ++i) {
        int row = nb * 64 + rgrp + i * 16;
        v[i] = *(const f32x4*)(w + (size_t)row * K + kb * 64 + cchk * 4);
        a = fmaxf(a, fmaxf(fmaxf(fabsf(v[i].x), fabsf(v[i].y)),
                           fmaxf(fabsf(v[i].z), fabsf(v[i].w))));
    }
#pragma unroll
    for (int off = 1; off < 64; off <<= 1) a = fmaxf(a, __shfl_xor(a, off));
    __shared__ float sm[4];
    if ((t & 63) == 0) sm[t >> 6] = a;
    __syncthreads();
    a = fmaxf(fmaxf(sm[0], sm[1]), fmaxf(sm[2], sm[3]));
    float scale = fmaxf(a, 1e-12f) / 448.0f;
#pragma unroll
    for (int i = 0; i < 4; ++i) {
        int row = nb * 64 + rgrp + i * 16;
        ushort4 o;
        o.x = f32_to_bf16_bits(qdq_e4m3(v[i].x / scale) * scale);
        o.y = f32_to_bf16_bits(qdq_e4m3(v[i].y / scale) * scale);
        o.z = f32_to_bf16_bits(qdq_e4m3(v[i].z / scale) * scale);
        o.w = f32_to_bf16_bits(qdq_e4m3(v[i].w / scale) * scale);
        *(ushort4*)(wq + (size_t)row * K + kb * 64 + cchk * 4) = o;
    }
}

// ---------- 256x256 bf16 GEMM, A[M,K] x B[N,K]^T ----------
// One barrier + one vmcnt(0) per K-tile; all 24 ds_reads issued up front in
// fenced groups; MFMA clusters gated by counted lgkmcnt(12/8/0) so LDS reads
// stream during MFMA. dbuf LDS w/ XOR swizzle; setprio; XCD swizzle.
#define GLDS(srcp, ldsp) __builtin_amdgcn_global_load_lds( \
    (__attribute__((address_space(1))) void*)(srcp),       \
    (__attribute__((address_space(3))) void*)(ldsp), 16, 0, 0)

__global__ __launch_bounds__(512, 2) void gemmdp(const unsigned short* __restrict__ A,
                                                 const unsigned short* __restrict__ B,
                                                 const float* __restrict__ bias,
                                                 float* __restrict__ C,
                                                 int M, int N, int K) {
    __shared__ unsigned short Al[2][256 * 64];
    __shared__ unsigned short Bl[2][256 * 64];
    const int tid = threadIdx.x;
    const int wid = tid >> 6;
    const int lane = tid & 63;
    const int wm = wid >> 2, wn = wid & 3;
    const int lrow = lane & 15, kh = lane >> 4;

    // XCD-aware bijective swizzle (nwg % 8 == 0 here: 512)
    const int nbx = N >> 8;
    const int nwg = (M >> 8) * nbx;
    const int bid = blockIdx.x;
    const int swz = (bid & 7) * (nwg >> 3) + (bid >> 3);
    const int tm = swz / nbx, tn = swz % nbx;

    const unsigned short* gA = A + (size_t)tm * 256 * K;
    const unsigned short* gB = B + (size_t)tn * 256 * K;

    const int srow = lane >> 3;                       // row within 8-row segment
    const int scolb = ((lane & 7) ^ srow) << 4;       // swizzled byte col [0,128)

    const int cLo = ((kh ^ (lane & 7)) << 4);         // k-chunk kh
    const int cHi = cLo ^ 64;                         // k-chunk kh+4 (= kh^4)

    const int NT = K >> 6;

    f32x4 acc[8][4];
#pragma unroll
    for (int m = 0; m < 8; ++m)
#pragma unroll
        for (int n = 0; n < 4; ++n) acc[m][n] = (f32x4){0.f, 0.f, 0.f, 0.f};

    s16x8 a0[4][2], a1[4][2], b0[2][2], b1[2][2];

    // stage full K-tile: 8 GLDS/wave (4 A-segments + 4 B-segments, 8 rows each)
    auto STG_ALL = [&](int t, int bufn) {
#pragma unroll
        for (int i = 0; i < 4; ++i) {
            int row = (wid * 4 + i) * 8;              // wave-uniform segment base
            GLDS((const char*)gA + ((size_t)(row + srow) * K + (size_t)t * 64) * 2 + scolb,
                 (char*)&Al[bufn][0] + row * 128);
            GLDS((const char*)gB + ((size_t)(row + srow) * K + (size_t)t * 64) * 2 + scolb,
                 (char*)&Bl[bufn][0] + row * 128);
        }
    };

    auto MM = [&](s16x8 (&aa)[4][2], s16x8 (&bb)[2][2], int mo, int no) {
#pragma unroll
        for (int m = 0; m < 4; ++m)
#pragma unroll
            for (int n = 0; n < 2; ++n) {
                acc[m + mo][n + no] = __builtin_amdgcn_mfma_f32_16x16x32_bf16(aa[m][0], bb[n][0], acc[m + mo][n + no], 0, 0, 0);
                acc[m + mo][n + no] = __builtin_amdgcn_mfma_f32_16x16x32_bf16(aa[m][1], bb[n][1], acc[m + mo][n + no], 0, 0, 0);
            }
    };

    const char* pAb[2] = {(const char*)&Al[0][0] + ((wm << 7) + lrow) * 128,
                          (const char*)&Al[1][0] + ((wm << 7) + lrow) * 128};
    const char* pBb[2] = {(const char*)&Bl[0][0] + ((wn << 6) + lrow) * 128,
                          (const char*)&Bl[1][0] + ((wn << 6) + lrow) * 128};

    STG_ALL(0, 0);   // prologue: tile 0 -> buf 0

    for (int t = 0; t < NT; ++t) {
        const int buf = t & 1;
        const char* pA = pAb[buf];
        const char* pB = pBb[buf];
        int t1 = t + 1; if (t1 == NT) t1 = 0;        // wrap (redundant last stage)

        // tile boundary: own staging drained, then all waves' staging + reads done
        asm volatile("s_waitcnt vmcnt(0)" ::: "memory");
        asm volatile("s_barrier" ::: "memory");

        STG_ALL(t1, buf ^ 1);                        // 8 GLDS for next tile

        // ---- issue all 24 ds_reads in 3 ordered groups ----
#pragma unroll
        for (int m = 0; m < 4; ++m) {                // group 1: a0 (8)
            a0[m][0] = *(const s16x8*)(pA + m * 2048 + cLo);
            a0[m][1] = *(const s16x8*)(pA + m * 2048 + cHi);
        }
#pragma unroll
        for (int n = 0; n < 2; ++n) {                // group 1: b0 (4)  -> 12 total
            b0[n][0] = *(const s16x8*)(pB + n * 2048 + cLo);
            b0[n][1] = *(const s16x8*)(pB + n * 2048 + cHi);
        }
        asm volatile("" ::: "memory");               // issue-order fence
#pragma unroll
        for (int n = 0; n < 2; ++n) {                // group 2: b1 (4)
            b1[n][0] = *(const s16x8*)(pB + (n + 2) * 2048 + cLo);
            b1[n][1] = *(const s16x8*)(pB + (n + 2) * 2048 + cHi);
        }
        asm volatile("" ::: "memory");               // issue-order fence
#pragma unroll
        for (int m = 0; m < 4; ++m) {                // group 3: a1 (8)
            a1[m][0] = *(const s16x8*)(pA + (m + 4) * 2048 + cLo);
            a1[m][1] = *(const s16x8*)(pA + (m + 4) * 2048 + cHi);
        }

        // ---- cluster 0: m0-3 x n0-1 (needs group 1; 12 newer reads in flight)
        __builtin_amdgcn_sched_barrier(0);
        asm volatile("s_waitcnt lgkmcnt(12)" ::: "memory");
        __builtin_amdgcn_sched_barrier(0);
        __builtin_amdgcn_s_setprio(1);
        MM(a0, b0, 0, 0);
        __builtin_amdgcn_s_setprio(0);

        // ---- cluster 1: m0-3 x n2-3 (needs group 2; 8 in flight)
        __builtin_amdgcn_sched_barrier(0);
        asm volatile("s_waitcnt lgkmcnt(8)" ::: "memory");
        __builtin_amdgcn_sched_barrier(0);
        __builtin_amdgcn_s_setprio(1);
        MM(a0, b1, 0, 2);
        __builtin_amdgcn_s_setprio(0);

        // ---- clusters 2+3: m4-7 x n2-3, m4-7 x n0-1 (b0 still live, no re-read)
        __builtin_amdgcn_sched_barrier(0);
        asm volatile("s_waitcnt lgkmcnt(0)" ::: "memory");
        __builtin_amdgcn_sched_barrier(0);
        __builtin_amdgcn_s_setprio(1);
        MM(a1, b1, 4, 2);
        MM(a1, b0, 4, 0);
        __builtin_amdgcn_s_setprio(0);
    }

    // epilogue: C/D layout col=lane&15, row=(lane>>4)*4+j
    const int gcol0 = tn * 256 + wn * 64 + lrow;
    const int grow0 = tm * 256 + wm * 128 + (lane >> 4) * 4;
#pragma unroll
    for (int n = 0; n < 4; ++n) {
        float bv = bias[gcol0 + n * 16];
#pragma unroll
        for (int m = 0; m < 8; ++m) {
#pragma unroll
            for (int j = 0; j < 4; ++j) {
                unsigned short b = f32_to_bf16_bits(acc[m][n][j]);
                C[(size_t)(grow0 + m * 16 + j) * N + gcol0 + n * 16] =
                    __uint_as_float(((unsigned int)b) << 16) + bv;
            }
        }
    }
}

extern "C" void kernel_launch(void* const* d_in, const int* in_sizes, int n_in,
                              void* d_out, int out_size, void* d_ws, size_t ws_size,
                              hipStream_t stream) {
    const float* x    = (const float*)d_in[0];
    const float* w    = (const float*)d_in[1];
    const float* bias = (const float*)d_in[2];
    float* out = (float*)d_out;

    const int N = in_sizes[2];
    const long long KL = (long long)in_sizes[1] / N;
    const int K = (int)KL;
    const int M = (int)((long long)in_sizes[0] / KL);

    unsigned short* xq = (unsigned short*)d_ws;
    unsigned short* wq = xq + (size_t)M * K;

    long long n4 = (long long)M * K / 4;
    quant_x_kernel<<<(unsigned)((n4 + 255) / 256), 256, 0, stream>>>(x, xq, n4);

    dim3 gw(K / 64, N / 64);
    quant_w_kernel<<<gw, 256, 0, stream>>>(w, wq, N, K);

    const int nwg = (M / 256) * (N / 256);
    gemmdp<<<nwg, 512, 0, stream>>>(xq, wq, bias, out, M, N, K);
}

// Round 6
// 331.247 us; speedup vs baseline: 1.3335x; 1.3335x over previous
//
#include <hip/hip_runtime.h>

typedef __attribute__((ext_vector_type(4))) float f32x4;
typedef __attribute__((ext_vector_type(2))) long i64x2;

// ---------- exact fp8 e4m3fn ENCODE (RNE, saturating), matching ml_dtypes ----------
__device__ __forceinline__ unsigned char enc_e4m3(float y) {
    unsigned int u = __float_as_uint(y);
    unsigned int s = (u >> 31) << 7;
    unsigned int a = u & 0x7fffffffu;
    if (a >= 0x3C800000u) {                       // |y| >= 2^-6: normal e4m3
        unsigned int r = a + 0x7FFFFu + ((a >> 20) & 1u);   // RNE to 3 mant bits
        r &= 0xFFF00000u;
        if (r > 0x43E00000u) r = 0x43E00000u;     // saturate 448
        unsigned int e = (r >> 23) - 120u;        // exp32-127+7
        return (unsigned char)(s | (e << 3) | ((r >> 20) & 7u));
    } else {                                      // subnormal: grid 2^-9
        int m = (int)rintf(__uint_as_float(a) * 512.0f);   // 0..8 (8 rolls to 2^-6)
        return (unsigned char)(s | (unsigned)m);
    }
}

__device__ __forceinline__ unsigned short f32_to_bf16_bits(float f) {
    unsigned int u = __float_as_uint(f);
    u += 0x7FFFu + ((u >> 16) & 1u);
    return (unsigned short)(u >> 16);
}

// interleaved column within a 64-K block: ONE 16B chunk holds both K=32 steps of a kh-group
__device__ __forceinline__ int ilv_col(int c) {   // c in [0,64)
    return ((c & 31) >> 3) * 16 + (c >> 5) * 8 + (c & 7);
}

// ---------- quantize x: per-row 1x64 tiles -> fp8 bytes (interleaved) + xsT[t][i] ----------
__global__ __launch_bounds__(256) void quant_x_kernel(const float* __restrict__ x,
                                                      unsigned char* __restrict__ xq,
                                                      float* __restrict__ xsT,
                                                      long long n4, int K, int M) {
    long long g = (long long)blockIdx.x * 256 + threadIdx.x;
    if (g >= n4) return;
    f32x4 v = ((const f32x4*)x)[g];
    float a = fmaxf(fmaxf(fabsf(v.x), fabsf(v.y)), fmaxf(fabsf(v.z), fabsf(v.w)));
    a = fmaxf(a, __shfl_xor(a, 1));
    a = fmaxf(a, __shfl_xor(a, 2));
    a = fmaxf(a, __shfl_xor(a, 4));
    a = fmaxf(a, __shfl_xor(a, 8));
    float scale = fmaxf(a, 1e-12f) / 448.0f;
    long long flat = g * 4;
    int row = (int)(flat / K);
    int rem = (int)(flat % K);
    int kb = rem >> 6, c0 = rem & 63;
    uchar4 o;
    o.x = enc_e4m3(v.x / scale);
    o.y = enc_e4m3(v.y / scale);
    o.z = enc_e4m3(v.z / scale);
    o.w = enc_e4m3(v.w / scale);
    *(uchar4*)(xq + (size_t)row * K + kb * 64 + ilv_col(c0)) = o;
    if ((c0 & 63) == 0)   // one lane per tile writes the scale
        xsT[(size_t)kb * M + row] = scale;
}

// ---------- quantize w: 64x64 blocks -> fp8 (interleaved) + ws[nb][kb] ----------
__global__ __launch_bounds__(256) void quant_w_kernel(const float* __restrict__ w,
                                                      unsigned char* __restrict__ wq,
                                                      float* __restrict__ ws,
                                                      int N, int K) {
    const int nb = blockIdx.y, kb = blockIdx.x;
    const int KT = K >> 6;
    const int t = threadIdx.x;
    const int rgrp = t >> 4;
    const int cchk = t & 15;
    f32x4 v[4];
    float a = 0.0f;
#pragma unroll
    for (int i = 0; i < 4; ++i) {
        int row = nb * 64 + rgrp + i * 16;
        v[i] = *(const f32x4*)(w + (size_t)row * K + kb * 64 + cchk * 4);
        a = fmaxf(a, fmaxf(fmaxf(fabsf(v[i].x), fabsf(v[i].y)),
                           fmaxf(fabsf(v[i].z), fabsf(v[i].w))));
    }
#pragma unroll
    for (int off = 1; off < 64; off <<= 1) a = fmaxf(a, __shfl_xor(a, off));
    __shared__ float sm[4];
    if ((t & 63) == 0) sm[t >> 6] = a;
    __syncthreads();
    a = fmaxf(fmaxf(sm[0], sm[1]), fmaxf(sm[2], sm[3]));
    float scale = fmaxf(a, 1e-12f) / 448.0f;
    const int oc = ilv_col(cchk * 4);
#pragma unroll
    for (int i = 0; i < 4; ++i) {
        int row = nb * 64 + rgrp + i * 16;
        uchar4 o;
        o.x = enc_e4m3(v[i].x / scale);
        o.y = enc_e4m3(v[i].y / scale);
        o.z = enc_e4m3(v[i].z / scale);
        o.w = enc_e4m3(v[i].w / scale);
        *(uchar4*)(wq + (size_t)row * K + kb * 64 + oc) = o;
    }
    if (t == 0) ws[(size_t)nb * KT + kb] = scale;
}

// ---------- 256x256 block-scaled fp8 GEMM, out = (qx sx) @ (qw sw)^T ----------
// Swapped-operand MFMA (W as A-operand) so xs is uniform per acc vector.
// fp8 halves LDS bytes AND instr count (interleaved b128 reads).
// One barrier + one vmcnt(0)/K-tile; counted lgkm per cluster; tail-read.
#define GLDS(srcp, ldsp) __builtin_amdgcn_global_load_lds( \
    (__attribute__((address_space(1))) void*)(srcp),       \
    (__attribute__((address_space(3))) void*)(ldsp), 16, 0, 0)

__global__ __launch_bounds__(512, 2) void gemm_fp8(const unsigned char* __restrict__ Aq,
                                                   const unsigned char* __restrict__ Bq,
                                                   const float* __restrict__ xsT,
                                                   const float* __restrict__ wss,
                                                   const float* __restrict__ bias,
                                                   float* __restrict__ C,
                                                   int M, int N, int K) {
    __shared__ unsigned char Al[2][256 * 64];
    __shared__ unsigned char Bl[2][256 * 64];
    const int tid = threadIdx.x;
    const int wid = tid >> 6;
    const int lane = tid & 63;
    const int wm = wid >> 2, wn = wid & 3;
    const int l15 = lane & 15;
    const int KT = K >> 6, NT = KT;

    // XCD-aware bijective swizzle (nwg = 512, %8==0)
    const int nbx = N >> 8;
    const int nwg = (M >> 8) * nbx;
    const int bid = blockIdx.x;
    const int swz = (bid & 7) * (nwg >> 3) + (bid >> 3);
    const int tm = swz / nbx, tn = swz % nbx;

    const unsigned char* gA = Aq + (size_t)tm * 256 * K;
    const unsigned char* gB = Bq + (size_t)tn * 256 * K;

    const int gswz = (((lane & 3) ^ (lane >> 4)) << 4);          // staging src col swizzle
    const int cSwz = (((lane >> 4) ^ ((lane >> 2) & 3)) << 4);   // ds_read col swizzle

    const int iRow = tm * 256 + wm * 128 + l15;   // X-row for scales/output
    const int jbw  = tn * 4 + wn;                 // W 64-block index

    f32x4 macc[4][8];                              // [nw][mx]
#pragma unroll
    for (int n = 0; n < 4; ++n)
#pragma unroll
        for (int m = 0; m < 8; ++m) macc[n][m] = (f32x4){0.f, 0.f, 0.f, 0.f};

    i64x2 xf[8], wf[4];
    float xsA[8], xsB[8], wsA = 0.f, wsB = 0.f;
    const f32x4 z4 = (f32x4){0.f, 0.f, 0.f, 0.f};

    auto STG = [&](int t, int bufn) {              // 4 GLDS/wave: full fp8 tiles
#pragma unroll
        for (int i = 0; i < 2; ++i) {
            int seg = wid * 2 + i;                 // 16 segs x 1KB (16 rows) per operand
            int row = seg * 16 + (lane >> 2);
            GLDS(gA + (size_t)row * K + (size_t)t * 64 + gswz, (char*)&Al[bufn][0] + seg * 1024);
            GLDS(gB + (size_t)row * K + (size_t)t * 64 + gswz, (char*)&Bl[bufn][0] + seg * 1024);
        }
    };

    const unsigned char* pAb[2] = {&Al[0][0] + (wm * 128 + l15) * 64 + cSwz,
                                   &Al[1][0] + (wm * 128 + l15) * 64 + cSwz};
    const unsigned char* pBb[2] = {&Bl[0][0] + (wn * 64 + l15) * 64 + cSwz,
                                   &Bl[1][0] + (wn * 64 + l15) * 64 + cSwz};

    // cluster: 4 mx x 2 nw fragments over K=64, then scale-FMA into macc
    auto CL = [&](int mo, int no, const float (&xs)[8], float wsv) {
#pragma unroll
        for (int mi = 0; mi < 4; ++mi) {
            float s = xs[mo + mi] * wsv;
#pragma unroll
            for (int ni = 0; ni < 2; ++ni) {
                f32x4 p = __builtin_amdgcn_mfma_f32_16x16x32_fp8_fp8(
                    wf[no + ni].x, xf[mo + mi].x, z4, 0, 0, 0);
                p = __builtin_amdgcn_mfma_f32_16x16x32_fp8_fp8(
                    wf[no + ni].y, xf[mo + mi].y, p, 0, 0, 0);
                macc[no + ni][mo + mi] += p * s;
            }
        }
    };

    // prologue: stage tile0 -> buf0, xs/ws for tile0
    STG(0, 0);
#pragma unroll
    for (int m = 0; m < 8; ++m) xsA[m] = xsT[iRow + m * 16];
    wsA = wss[(size_t)jbw * KT];
    asm volatile("s_waitcnt vmcnt(0)" ::: "memory");
    asm volatile("s_barrier" ::: "memory");
#pragma unroll
    for (int m = 0; m < 4; ++m) xf[m] = *(const i64x2*)(pAb[0] + m * 1024);
#pragma unroll
    for (int n = 0; n < 2; ++n) wf[n] = *(const i64x2*)(pBb[0] + n * 1024);

    auto TILE = [&](int buf, int tnx, const float (&xsC)[8], float wsC,
                    float (&xsN)[8], float& wsN) {
        const unsigned char* pA = pAb[buf];
        const unsigned char* pB = pBb[buf];
        const unsigned char* pAn = pAb[buf ^ 1];
        const unsigned char* pBn = pBb[buf ^ 1];

        // ph0: stage next tile + prefetch its scales; read wf2-3; c0
        STG(tnx, buf ^ 1);
#pragma unroll
        for (int m = 0; m < 8; ++m) xsN[m] = xsT[(size_t)tnx * M + iRow + m * 16];
        wsN = wss[(size_t)jbw * KT + tnx];
#pragma unroll
        for (int n = 0; n < 2; ++n) wf[n + 2] = *(const i64x2*)(pB + (n + 2) * 1024);
        asm volatile("s_waitcnt lgkmcnt(2)" ::: "memory");
        __builtin_amdgcn_sched_barrier(0);
        __builtin_amdgcn_s_setprio(1);
        CL(0, 0, xsC, wsC);
        __builtin_amdgcn_s_setprio(0);

        // ph1: read xf4-7; c1
#pragma unroll
        for (int m = 0; m < 4; ++m) xf[m + 4] = *(const i64x2*)(pA + (m + 4) * 1024);
        asm volatile("s_waitcnt lgkmcnt(4)" ::: "memory");
        __builtin_amdgcn_sched_barrier(0);
        __builtin_amdgcn_s_setprio(1);
        CL(0, 2, xsC, wsC);
        __builtin_amdgcn_s_setprio(0);

        // ph2: c2
        asm volatile("s_waitcnt lgkmcnt(0)" ::: "memory");
        __builtin_amdgcn_sched_barrier(0);
        __builtin_amdgcn_s_setprio(1);
        CL(4, 2, xsC, wsC);
        __builtin_amdgcn_s_setprio(0);

        // ph3: c3 (all frags live); then tile boundary + tail-read next c0
        __builtin_amdgcn_s_setprio(1);
        CL(4, 0, xsC, wsC);
        __builtin_amdgcn_s_setprio(0);
        asm volatile("s_waitcnt vmcnt(0)" ::: "memory");   // next buf fully staged (own wave)
        asm volatile("s_barrier" ::: "memory");            // join all waves
#pragma unroll
        for (int m = 0; m < 4; ++m) xf[m] = *(const i64x2*)(pAn + m * 1024);
#pragma unroll
        for (int n = 0; n < 2; ++n) wf[n] = *(const i64x2*)(pBn + n * 1024);
    };

    for (int t = 0; t < NT; t += 2) {
        int t1 = t + 1;
        int t2 = (t + 2 < NT) ? (t + 2) : 0;     // wrap: redundant but uniform
        TILE(0, t1, xsA, wsA, xsB, wsB);
        TILE(1, t2, xsB, wsB, xsA, wsA);
    }

    // epilogue: D col = lane&15 -> X-row; D row = (lane>>4)*4+j -> W-col (contiguous f32x4)
    const int jc0 = tn * 256 + wn * 64 + (lane >> 4) * 4;
#pragma unroll
    for (int ni = 0; ni < 4; ++ni) {
        f32x4 bv = *(const f32x4*)(bias + jc0 + ni * 16);
#pragma unroll
        for (int mi = 0; mi < 8; ++mi) {
            f32x4 vo;
#pragma unroll
            for (int j = 0; j < 4; ++j) {
                unsigned short b = f32_to_bf16_bits(macc[ni][mi][j]);
                vo[j] = __uint_as_float(((unsigned int)b) << 16) + bv[j];
            }
            *(f32x4*)(C + (size_t)(iRow + mi * 16) * N + jc0 + ni * 16) = vo;
        }
    }
}

extern "C" void kernel_launch(void* const* d_in, const int* in_sizes, int n_in,
                              void* d_out, int out_size, void* d_ws, size_t ws_size,
                              hipStream_t stream) {
    const float* x    = (const float*)d_in[0];
    const float* w    = (const float*)d_in[1];
    const float* bias = (const float*)d_in[2];
    float* out = (float*)d_out;

    const int N = in_sizes[2];
    const long long KL = (long long)in_sizes[1] / N;
    const int K = (int)KL;
    const int M = (int)((long long)in_sizes[0] / KL);
    const int KT = K / 64;

    unsigned char* xq = (unsigned char*)d_ws;                       // M*K fp8
    unsigned char* wq = xq + (size_t)M * K;                         // N*K fp8
    float* xsT = (float*)(wq + (size_t)N * K);                      // KT*M f32
    float* wss = xsT + (size_t)KT * M;                              // (N/64)*KT f32

    long long n4 = (long long)M * K / 4;
    quant_x_kernel<<<(unsigned)((n4 + 255) / 256), 256, 0, stream>>>(x, xq, xsT, n4, K, M);

    dim3 gw(K / 64, N / 64);
    quant_w_kernel<<<gw, 256, 0, stream>>>(w, wq, wss, N, K);

    const int nwg = (M / 256) * (N / 256);
    gemm_fp8<<<nwg, 512, 0, stream>>>(xq, wq, xsT, wss, bias, out, M, N, K);
}